// Round 13
// baseline (120.320 us; speedup 1.0000x reference)
//
#include <hip/hip_runtime.h>
#include <hip/hip_bf16.h>

#define NCAT 72
#define NCATP 80          // padded to 5 MFMA cat-tiles of 16
#define DIM 32
#define ROWS 36           // k_accum LDS row stride: 144B, 16B-aligned, 4-bank rotation/label
#define BNUM 4
#define TEMP_INV (1.0f / 0.07f)
#define SEG_W 10.0f

// ws layout (floats):
#define WS_SUMS 0         // [4][72][32]
#define WS_CNTS 9216      // [4][72]
#define WS_PROT 9504      // [4][80][32]  normalized prototypes, PADDED, absent/missing rows ZERO
#define WS_NABS 19744     // [4]          count of zero rows (exp2 contributes exactly 1 each)
#define WS_LOSS 19748     // [4]
#define WS_KEEP 19752     // [4]
#define WS_TOTAL 19756

typedef __attribute__((ext_vector_type(8))) short short8v;   // 8 bf16
typedef __attribute__((ext_vector_type(4))) float f32x4;
typedef __attribute__((ext_vector_type(4))) unsigned u32x4;

__device__ __forceinline__ bool is_missing(int c) {
    return (c == 13) | (c == 53) | (c == 61);
}

// float -> bf16(RNE) bits, and the fp32 value of that bf16 (for lo-split)
__device__ __forceinline__ short f2bf_hi(float f, float* hi_f) {
    unsigned u = __float_as_uint(f);
    unsigned r = u + 0x7FFFu + ((u >> 16) & 1u);
    *hi_f = __uint_as_float(r & 0xFFFF0000u);
    return (short)(r >> 16);
}
__device__ __forceinline__ short f2bf(float f) {
    unsigned u = __float_as_uint(f);
    unsigned r = u + 0x7FFFu + ((u >> 16) & 1u);
    return (short)(r >> 16);
}

// packed f32x2 -> bf16x2 (low16 = bf16(a)); no builtin on gfx950 (m240)
__device__ __forceinline__ unsigned cvtpk_bf16(float a, float b) {
    unsigned r;
    asm("v_cvt_pk_bf16_f32 %0, %1, %2" : "=v"(r) : "v"(a), "v"(b));
    return r;
}

// k_accum v4 (R8: collision-resolved commit; R11: folds reverted).
// Probe+ballot rounds: winners (wave-unique labels) commit float4 rows
// concurrently, losers retry (~1.4 rounds avg). LDS-capped at 3 blocks/CU.
template <int BPB>
__global__ __launch_bounds__(256) void k_accum(const float* __restrict__ emb,
                                               const int* __restrict__ lab,
                                               float* __restrict__ ws, int Nb) {
    __shared__ float s_acc[4][NCAT][ROWS];  // per-wave private, 41.5 KB
    __shared__ float s_cnt[4][NCAT];
    __shared__ int   s_prb[4][NCAT];
    const int t = threadIdx.x;
    const int b = blockIdx.x / BPB;
    const int blk = blockIdx.x % BPB;
    const int w = t >> 6;         // wave 0..3
    const int g = (t >> 3) & 7;   // point-slot within wave
    const int sub = t & 7;        // float4 index within point
    const int pofs = t >> 3;      // 0..31: point slot within block

    for (int i = t; i < 4 * NCAT * ROWS; i += 256) ((float*)s_acc)[i] = 0.f;
    for (int i = t; i < 4 * NCAT; i += 256) ((float*)s_cnt)[i] = 0.f;
    __syncthreads();

    float* accw = &s_acc[w][0][0];
    int* prbw = &s_prb[w][0];
    const float* eb = emb + (size_t)b * Nb * DIM;
    const int* lb = lab + (size_t)b * Nb;

    int p = blk * 32 + pofs;
    int l_cur = lb[p];
    float4 v_cur = ((const float4*)(eb + (size_t)p * DIM))[sub];

    for (int p0 = blk * 32; p0 < Nb; p0 += BPB * 32) {
        const int pn = p0 + BPB * 32 + pofs;
        int l_nxt = -1;
        float4 v_nxt = make_float4(0.f, 0.f, 0.f, 0.f);
        if (pn < Nb) {
            l_nxt = lb[pn];
            v_nxt = ((const float4*)(eb + (size_t)pn * DIM))[sub];
        }

        float ss = v_cur.x * v_cur.x + v_cur.y * v_cur.y +
                   v_cur.z * v_cur.z + v_cur.w * v_cur.w;
        ss += __shfl_xor(ss, 1);
        ss += __shfl_xor(ss, 2);
        ss += __shfl_xor(ss, 4);
        const float inv = 1.0f / fmaxf(sqrtf(ss), 1e-12f);
        const bool valid = (l_cur >= 0);
        const int lc = min(max(l_cur, 0), NCAT - 1);
        float4 u;
        u.x = v_cur.x * inv; u.y = v_cur.y * inv;
        u.z = v_cur.z * inv; u.w = v_cur.w * inv;

        if (valid && sub == 0) unsafeAtomicAdd(&s_cnt[w][lc], 1.0f);

        float* rowp = accw + lc * ROWS + sub * 4;
        bool active = valid;
        while (__any(active)) {
            asm volatile("" ::: "memory");   // force row re-read each round
            if (active && sub == 0) prbw[lc] = g;          // last-writer-wins
            int win = 0;
            if (active && sub == 0) win = (prbw[lc] == g) ? 1 : 0;
            const unsigned long long wb = __ballot(win);
            const bool iwin = active && ((wb >> (g * 8)) & 1ull);
            if (iwin) {                      // winners have distinct labels
                float4* r4 = (float4*)rowp;
                float4 o = *r4;
                o.x += u.x; o.y += u.y; o.z += u.z; o.w += u.w;
                *r4 = o;
            }
            active = active && !iwin;
        }

        l_cur = l_nxt;
        v_cur = v_nxt;
    }
    __syncthreads();

    float* gs = ws + WS_SUMS + b * NCAT * DIM;
    for (int i = t; i < NCAT * DIM; i += 256) {
        const int c = i >> 5, d = i & 31;
        float val = s_acc[0][c][d] + s_acc[1][c][d] +
                    s_acc[2][c][d] + s_acc[3][c][d];
        if (val != 0.f) unsafeAtomicAdd(&gs[i], val);
    }
    if (t < NCAT) {
        float c = s_cnt[0][t] + s_cnt[1][t] + s_cnt[2][t] + s_cnt[3][t];
        if (c != 0.f) unsafeAtomicAdd(ws + WS_CNTS + b * NCAT + t, c);
    }
}

// One block per batch: normalize sums -> prototypes (padded, absent rows ZERO)
// and store n_absent = count of zero rows (incl. 8 pad rows).
__global__ __launch_bounds__(256) void k_proto(float* __restrict__ ws) {
    const int b = blockIdx.x;
    __shared__ float s_np;
    if (threadIdx.x == 0) s_np = 0.f;
    __syncthreads();
    const float* gs = ws + WS_SUMS + b * NCAT * DIM;
    const float* gc = ws + WS_CNTS + b * NCAT;
    float* gp = ws + WS_PROT + b * NCATP * DIM;
    const int dd = threadIdx.x & 31;
    const int r0 = threadIdx.x >> 5;
    for (int c = r0; c < NCAT; c += 8) {
        float cnt = gc[c];
        float val = gs[c * DIM + dd] / fmaxf(cnt, 1.0f);
        float ss = val * val;
        #pragma unroll
        for (int m = 16; m >= 1; m >>= 1) ss += __shfl_xor(ss, m);
        float inv = 1.0f / fmaxf(sqrtf(ss), 1e-12f);
        const bool present = (cnt > 0.f) && !is_missing(c);
        gp[c * DIM + dd] = present ? val * inv : 0.f;  // zero row -> exp2 term exactly 1
        if (dd == 0) unsafeAtomicAdd(&s_np, present ? 1.f : 0.f);
        // rows 72..79 remain zero from the memset
    }
    __syncthreads();
    if (threadIdx.x == 0) ws[WS_NABS + b] = (float)NCATP - s_np;
}

// k_loss v10 point group (= v9 math: LDS prototype fragments, raw-e MFMA
// with rsqrt post-scale, C-fragment label logit).
__device__ __forceinline__ void point_group(
    int pt, int l, const float* __restrict__ eb,
    const u32x4 (*__restrict__ sf)[64], int lane,
    float nabs, int sub, float& lacc, float& dacc, float& kacc)
{
    const float LOG2E = 1.4426950408889634f;
    const int lc = min(max(l, 0), NCAT - 1);

    const float4* ep = (const float4*)(eb + (size_t)pt * DIM + sub * 8);
    float4 a0 = ep[0], a1 = ep[1];

    // bf16 hi/lo split of the RAW point (independent of the norm)
    float ea[8] = {a0.x, a0.y, a0.z, a0.w, a1.x, a1.y, a1.z, a1.w};
    u32x4 hw, lw;
    #pragma unroll
    for (int j = 0; j < 4; j++) {
        const float x0 = ea[2 * j], x1 = ea[2 * j + 1];
        const unsigned h = cvtpk_bf16(x0, x1);
        const float h0 = __uint_as_float(h << 16);
        const float h1 = __uint_as_float(h & 0xFFFF0000u);
        hw[j] = h;
        lw[j] = cvtpk_bf16(x0 - h0, x1 - h1);
    }
    const short8v ehi = __builtin_bit_cast(short8v, hw);
    const short8v elo = __builtin_bit_cast(short8v, lw);

    // norm -> post-scale factor (runs beside the MFMA chain)
    float ss = a0.x * a0.x + a0.y * a0.y + a0.z * a0.z + a0.w * a0.w +
               a1.x * a1.x + a1.y * a1.y + a1.z * a1.z + a1.w * a1.w;
    ss += __shfl_xor(ss, 16);
    ss += __shfl_xor(ss, 32);
    const float kk = (TEMP_INV * LOG2E) * __builtin_amdgcn_rsqf(fmaxf(ss, 1e-24f));

    const bool keep = (l >= 0) && !is_missing(lc);
    const int ltile = lc >> 4;                         // which 16-cat tile
    const bool qm = keep && (((lc >> 2) & 3) == sub);  // my sub holds the label row-quad

    // 5 cat-tiles: C col=point(lane&15), row=cat-in-tile=(sub*4+reg)
    float s = 0.f;
    #pragma unroll
    for (int n = 0; n < 5; n++) {
        const short8v phn = __builtin_bit_cast(short8v, sf[n * 2][lane]);
        const short8v pln = __builtin_bit_cast(short8v, sf[n * 2 + 1][lane]);
        f32x4 acc = {0.f, 0.f, 0.f, 0.f};
        acc = __builtin_amdgcn_mfma_f32_16x16x32_bf16(phn, ehi, acc, 0, 0, 0);
        acc = __builtin_amdgcn_mfma_f32_16x16x32_bf16(pln, ehi, acc, 0, 0, 0);
        acc = __builtin_amdgcn_mfma_f32_16x16x32_bf16(phn, elo, acc, 0, 0, 0);
        s += __builtin_amdgcn_exp2f(acc[0] * kk) + __builtin_amdgcn_exp2f(acc[1] * kk) +
             __builtin_amdgcn_exp2f(acc[2] * kk) + __builtin_amdgcn_exp2f(acc[3] * kk);
        if (qm && ltile == n) {                 // label logit straight from C
            const float d01 = (lc & 1) ? acc[1] : acc[0];
            const float d23 = (lc & 1) ? acc[3] : acc[2];
            dacc += kk * ((lc & 2) ? d23 : d01);
        }
    }
    s += __shfl_xor(s, 16);
    s += __shfl_xor(s, 32);
    s -= nabs;                       // remove the exactly-1 terms of zero rows
    const float cl = __builtin_amdgcn_logf(s);   // log2
    if (keep && sub == 0) {
        lacc += cl;
        kacc += 1.f;
    }
}

// k_loss v10: ILP-1 + TLP.
// R12 synthesis: R4's counters said latency-bound (VALU 37%); ILP probes
// (v5 2-way, v6 4-way) were null because under the (256,4) 128-VGPR cap the
// allocator SEQUENTIALIZES the "independent" groups' live ranges -- in-wave
// ILP is dead here. Instead: single group per iteration (live set ~50 regs)
// + __launch_bounds__(256,6) + 6 blocks/CU grid -> 24 waves/CU (+50% TLP).
template <int BPB>
__global__ __launch_bounds__(256, 6) void k_loss(const float* __restrict__ emb,
                                                 const int* __restrict__ lab,
                                                 const float* __restrict__ protos,
                                                 const float* __restrict__ nabsp,
                                                 float* __restrict__ lossout,
                                                 int Nb) {
    __shared__ u32x4 s_frag[10][64];   // [tile*2+half][lane], 10.25 KB
    __shared__ float s_red[8];
    const int b = blockIdx.x / BPB;
    const int blk = blockIdx.x % BPB;
    const int t = threadIdx.x;
    const int lane = t & 63;
    const int wave = t >> 6;
    const int lid = lane & 15;   // A: cat-in-tile / B: point / C: point col
    const int sub = lane >> 4;   // k-chunk (A,B) / cat row-quad (C)

    const float* pp = protos + b * NCATP * DIM;
    const float nabs = nabsp[b];
    const float* eb = emb + (size_t)b * Nb * DIM;
    const int* lb = lab + (size_t)b * Nb;
    const float LN2 = 0.6931471805599453f;

    // ---- prototype fragments -> LDS, built once by wave 0 ----
    if (wave == 0) {
        #pragma unroll
        for (int n = 0; n < 5; n++) {
            const int cat = n * 16 + lid;
            const float4* qk = (const float4*)(pp + cat * DIM + sub * 8);
            float4 q0 = qk[0], q1 = qk[1];
            float qa[8] = {q0.x, q0.y, q0.z, q0.w, q1.x, q1.y, q1.z, q1.w};
            short8v hi8, lo8;
            #pragma unroll
            for (int j = 0; j < 8; j++) {
                float hf;
                hi8[j] = f2bf_hi(qa[j], &hf);
                lo8[j] = f2bf(qa[j] - hf);
            }
            s_frag[n * 2][lane] = __builtin_bit_cast(u32x4, hi8);
            s_frag[n * 2 + 1][lane] = __builtin_bit_cast(u32x4, lo8);
        }
    }
    __syncthreads();

    float lacc = 0.f, dacc = 0.f, kacc = 0.f;

    #pragma unroll 1
    for (int p0 = (blk * 4 + wave) * 16; p0 < Nb; p0 += BPB * 4 * 16) {
        const int l = lb[p0 + lid];   // 16 consecutive ints, broadcast-coalesced
        point_group(p0 + lid, l, eb, s_frag, lane, nabs, sub, lacc, dacc, kacc);
    }

    // v = sum(log2 sums) - sum(label logits); k = kept count
    float v = lacc - dacc;
    #pragma unroll
    for (int m = 32; m >= 1; m >>= 1) {
        v += __shfl_xor(v, m);
        kacc += __shfl_xor(kacc, m);
    }
    if (lane == 0) {
        s_red[wave] = v;
        s_red[4 + wave] = kacc;
    }
    __syncthreads();
    if (t == 0) {
        float a = s_red[0] + s_red[1] + s_red[2] + s_red[3];
        float k = s_red[4] + s_red[5] + s_red[6] + s_red[7];
        unsafeAtomicAdd(lossout + b, LN2 * a);      // WS_LOSS (ln-space)
        unsafeAtomicAdd(lossout + BNUM + b, k);     // WS_KEEP
    }
}

__global__ void k_final(const float* __restrict__ ws, float* __restrict__ out) {
    if (threadIdx.x == 0 && blockIdx.x == 0) {
        float s = 0.f;
        for (int b = 0; b < BNUM; b++) {
            float l = ws[WS_LOSS + b];
            float k = ws[WS_KEEP + b];
            s += l / fmaxf(k, 1.0f);
        }
        out[0] = SEG_W * (s / BNUM);
    }
}

extern "C" void kernel_launch(void* const* d_in, const int* in_sizes, int n_in,
                              void* d_out, int out_size, void* d_ws, size_t ws_size,
                              hipStream_t stream) {
    const float* emb = (const float*)d_in[0];
    const int* lab = (const int*)d_in[1];
    float* ws = (float*)d_ws;
    float* out = (float*)d_out;
    const int total_pts = in_sizes[1];
    const int Nb = total_pts / BNUM;

    hipMemsetAsync(d_ws, 0, WS_TOTAL * sizeof(float), stream);
    constexpr int BPB_ACC = 192;   // 768 blocks -> 3 blocks/CU exact (LDS ~44KB/block)
    constexpr int BPB_LOSS = 384;  // 1536 blocks -> 6 blocks/CU exact, 24 waves/CU
    k_accum<BPB_ACC><<<dim3(BNUM * BPB_ACC), dim3(256), 0, stream>>>(emb, lab, ws, Nb);
    k_proto<<<dim3(BNUM), dim3(256), 0, stream>>>(ws);
    k_loss<BPB_LOSS><<<dim3(BNUM * BPB_LOSS), dim3(256), 0, stream>>>(
        emb, lab, ws + WS_PROT, ws + WS_NABS, ws + WS_LOSS, Nb);
    k_final<<<1, 64, 0, stream>>>(ws, out);
}

// Round 14
// 110.159 us; speedup vs baseline: 1.0922x; 1.0922x over previous
//
#include <hip/hip_runtime.h>
#include <hip/hip_bf16.h>

#define NCAT 72
#define NCATP 80          // padded to 5 MFMA cat-tiles of 16
#define DIM 32
#define ROWS 36           // k_accum LDS row stride: 144B, 16B-aligned, 4-bank rotation/label
#define BNUM 4
#define TEMP_INV (1.0f / 0.07f)
#define SEG_W 10.0f

// ws layout (floats) -- protos/nabs no longer materialized (built in k_loss):
#define WS_SUMS 0         // [4][72][32]
#define WS_CNTS 9216      // [4][72]
#define WS_LOSS 9504      // [4]
#define WS_KEEP 9508      // [4]
#define WS_TOTAL 9512

typedef __attribute__((ext_vector_type(8))) short short8v;   // 8 bf16
typedef __attribute__((ext_vector_type(4))) float f32x4;
typedef __attribute__((ext_vector_type(4))) unsigned u32x4;

__device__ __forceinline__ bool is_missing(int c) {
    return (c == 13) | (c == 53) | (c == 61);
}

// float -> bf16(RNE) bits, and the fp32 value of that bf16 (for lo-split)
__device__ __forceinline__ short f2bf_hi(float f, float* hi_f) {
    unsigned u = __float_as_uint(f);
    unsigned r = u + 0x7FFFu + ((u >> 16) & 1u);
    *hi_f = __uint_as_float(r & 0xFFFF0000u);
    return (short)(r >> 16);
}
__device__ __forceinline__ short f2bf(float f) {
    unsigned u = __float_as_uint(f);
    unsigned r = u + 0x7FFFu + ((u >> 16) & 1u);
    return (short)(r >> 16);
}

// packed f32x2 -> bf16x2 (low16 = bf16(a)); no builtin on gfx950 (m240)
__device__ __forceinline__ unsigned cvtpk_bf16(float a, float b) {
    unsigned r;
    asm("v_cvt_pk_bf16_f32 %0, %1, %2" : "=v"(r) : "v"(a), "v"(b));
    return r;
}

// k_accum v6 (register-scheduled commit).
// R13 diagnosis: v4's probe+ballot still pays ~1.4 DEPENDENT LDS round-trips
// per iteration (probe-write -> wait -> probe-read -> ballot) -- serial
// latency nothing hides at 22% occupancy. v6 computes the commit schedule in
// registers: 8 shfl exchange the slot labels (available at iteration start,
// labels prefetched), myr = #earlier slots with same label (~25 VALU,
// overlappable), then myr-masked commit rounds. Each thread commits exactly
// once -> no probe, no re-read, no asm clobber. sched_barrier(0) pins round
// order; the in-order LDS pipe orders same-row RMWs across rounds (v2/v4's
// proven mechanism).
template <int BPB>
__global__ __launch_bounds__(256) void k_accum(const float* __restrict__ emb,
                                               const int* __restrict__ lab,
                                               float* __restrict__ ws, int Nb) {
    __shared__ float s_acc[4][NCAT][ROWS];  // per-wave private, 41.5 KB
    __shared__ float s_cnt[4][NCAT];
    const int t = threadIdx.x;
    const int b = blockIdx.x / BPB;
    const int blk = blockIdx.x % BPB;
    const int w = t >> 6;         // wave 0..3
    const int g = (t >> 3) & 7;   // point-slot within wave
    const int sub = t & 7;        // float4 index within point
    const int pofs = t >> 3;      // 0..31: point slot within block

    for (int i = t; i < 4 * NCAT * ROWS; i += 256) ((float*)s_acc)[i] = 0.f;
    for (int i = t; i < 4 * NCAT; i += 256) ((float*)s_cnt)[i] = 0.f;
    __syncthreads();

    float* accw = &s_acc[w][0][0];
    const float* eb = emb + (size_t)b * Nb * DIM;
    const int* lb = lab + (size_t)b * Nb;

    int p = blk * 32 + pofs;
    int l_cur = lb[p];
    float4 v_cur = ((const float4*)(eb + (size_t)p * DIM))[sub];

    for (int p0 = blk * 32; p0 < Nb; p0 += BPB * 32) {
        const int pn = p0 + BPB * 32 + pofs;
        int l_nxt = -1;
        float4 v_nxt = make_float4(0.f, 0.f, 0.f, 0.f);
        if (pn < Nb) {
            l_nxt = lb[pn];
            v_nxt = ((const float4*)(eb + (size_t)pn * DIM))[sub];
        }

        // ---- commit schedule from registers (l_cur ready since last iter) ----
        const bool valid = (l_cur >= 0);
        const int lc = min(max(l_cur, 0), NCAT - 1);
        const int key = valid ? lc : (-1 - g);   // invalid slots never match
        const int k0 = __shfl(key, 0),  k1 = __shfl(key, 8);
        const int k2 = __shfl(key, 16), k3 = __shfl(key, 24);
        const int k4 = __shfl(key, 32), k5 = __shfl(key, 40);
        const int k6 = __shfl(key, 48);
        int myr = 0;
        myr += (g > 0 && k0 == key);
        myr += (g > 1 && k1 == key);
        myr += (g > 2 && k2 == key);
        myr += (g > 3 && k3 == key);
        myr += (g > 4 && k4 == key);
        myr += (g > 5 && k5 == key);
        myr += (g > 6 && k6 == key);

        float ss = v_cur.x * v_cur.x + v_cur.y * v_cur.y +
                   v_cur.z * v_cur.z + v_cur.w * v_cur.w;
        ss += __shfl_xor(ss, 1);
        ss += __shfl_xor(ss, 2);
        ss += __shfl_xor(ss, 4);
        const float inv = 1.0f / fmaxf(sqrtf(ss), 1e-12f);
        float4 u;
        u.x = v_cur.x * inv; u.y = v_cur.y * inv;
        u.z = v_cur.z * inv; u.w = v_cur.w * inv;

        if (valid && sub == 0) unsafeAtomicAdd(&s_cnt[w][lc], 1.0f);

        float* rowp = accw + lc * ROWS + sub * 4;
        for (int r = 0; ; ++r) {
            if (valid && myr == r) {             // round-r owners: wave-unique rows
                float4* r4 = (float4*)rowp;
                float4 o = *r4;
                o.x += u.x; o.y += u.y; o.z += u.z; o.w += u.w;
                *r4 = o;
            }
            __builtin_amdgcn_sched_barrier(0);   // keep rounds distinct & ordered
            if (!__any(valid && myr > r)) break;
        }

        l_cur = l_nxt;
        v_cur = v_nxt;
    }
    __syncthreads();

    float* gs = ws + WS_SUMS + b * NCAT * DIM;
    for (int i = t; i < NCAT * DIM; i += 256) {
        const int c = i >> 5, d = i & 31;
        float val = s_acc[0][c][d] + s_acc[1][c][d] +
                    s_acc[2][c][d] + s_acc[3][c][d];
        if (val != 0.f) unsafeAtomicAdd(&gs[i], val);
    }
    if (t < NCAT) {
        float c = s_cnt[0][t] + s_cnt[1][t] + s_cnt[2][t] + s_cnt[3][t];
        if (c != 0.f) unsafeAtomicAdd(ws + WS_CNTS + b * NCAT + t, c);
    }
}

// k_loss point group (v9 math: LDS prototype fragments, raw-e MFMA with
// rsqrt post-scale, C-fragment label logit). Unchanged from R11 (113.0us).
__device__ __forceinline__ void point_group(
    int pt, int l, const float* __restrict__ eb,
    const u32x4 (*__restrict__ sf)[64], int lane,
    float nabs, int sub, float& lacc, float& dacc, float& kacc)
{
    const float LOG2E = 1.4426950408889634f;
    const int lc = min(max(l, 0), NCAT - 1);

    const float4* ep = (const float4*)(eb + (size_t)pt * DIM + sub * 8);
    float4 a0 = ep[0], a1 = ep[1];

    // bf16 hi/lo split of the RAW point (independent of the norm)
    float ea[8] = {a0.x, a0.y, a0.z, a0.w, a1.x, a1.y, a1.z, a1.w};
    u32x4 hw, lw;
    #pragma unroll
    for (int j = 0; j < 4; j++) {
        const float x0 = ea[2 * j], x1 = ea[2 * j + 1];
        const unsigned h = cvtpk_bf16(x0, x1);
        const float h0 = __uint_as_float(h << 16);
        const float h1 = __uint_as_float(h & 0xFFFF0000u);
        hw[j] = h;
        lw[j] = cvtpk_bf16(x0 - h0, x1 - h1);
    }
    const short8v ehi = __builtin_bit_cast(short8v, hw);
    const short8v elo = __builtin_bit_cast(short8v, lw);

    // norm -> post-scale factor (runs beside the MFMA chain)
    float ss = a0.x * a0.x + a0.y * a0.y + a0.z * a0.z + a0.w * a0.w +
               a1.x * a1.x + a1.y * a1.y + a1.z * a1.z + a1.w * a1.w;
    ss += __shfl_xor(ss, 16);
    ss += __shfl_xor(ss, 32);
    const float kk = (TEMP_INV * LOG2E) * __builtin_amdgcn_rsqf(fmaxf(ss, 1e-24f));

    const bool keep = (l >= 0) && !is_missing(lc);
    const int ltile = lc >> 4;                         // which 16-cat tile
    const bool qm = keep && (((lc >> 2) & 3) == sub);  // my sub holds the label row-quad

    // 5 cat-tiles: C col=point(lane&15), row=cat-in-tile=(sub*4+reg)
    float s = 0.f;
    #pragma unroll
    for (int n = 0; n < 5; n++) {
        const short8v phn = __builtin_bit_cast(short8v, sf[n * 2][lane]);
        const short8v pln = __builtin_bit_cast(short8v, sf[n * 2 + 1][lane]);
        f32x4 acc = {0.f, 0.f, 0.f, 0.f};
        acc = __builtin_amdgcn_mfma_f32_16x16x32_bf16(phn, ehi, acc, 0, 0, 0);
        acc = __builtin_amdgcn_mfma_f32_16x16x32_bf16(pln, ehi, acc, 0, 0, 0);
        acc = __builtin_amdgcn_mfma_f32_16x16x32_bf16(phn, elo, acc, 0, 0, 0);
        s += __builtin_amdgcn_exp2f(acc[0] * kk) + __builtin_amdgcn_exp2f(acc[1] * kk) +
             __builtin_amdgcn_exp2f(acc[2] * kk) + __builtin_amdgcn_exp2f(acc[3] * kk);
        if (qm && ltile == n) {                 // label logit straight from C
            const float d01 = (lc & 1) ? acc[1] : acc[0];
            const float d23 = (lc & 1) ? acc[3] : acc[2];
            dacc += kk * ((lc & 2) ? d23 : d01);
        }
    }
    s += __shfl_xor(s, 16);
    s += __shfl_xor(s, 32);
    s -= nabs;                       // remove the exactly-1 terms of zero rows
    const float cl = __builtin_amdgcn_logf(s);   // log2
    if (keep && sub == 0) {
        lacc += cl;
        kacc += 1.f;
    }
}

// k_loss v11 = R11's v9b loop (4 groups/iter, (256,4), BPB=256 -- the
// measured-best config) + IN-BLOCK proto build: wave 0 reads sums/counts
// and normalizes while building the LDS fragments, replacing the k_proto
// dispatch (identical formula; nabs via ballot-popcount).
template <int BPB>
__global__ __launch_bounds__(256, 4) void k_loss(const float* __restrict__ emb,
                                                 const int* __restrict__ lab,
                                                 const float* __restrict__ ws,
                                                 float* __restrict__ lossout,
                                                 int Nb) {
    __shared__ u32x4 s_frag[10][64];   // [tile*2+half][lane], 10.25 KB
    __shared__ float s_red[8];
    __shared__ float s_nabs;
    const int b = blockIdx.x / BPB;
    const int blk = blockIdx.x % BPB;
    const int t = threadIdx.x;
    const int lane = t & 63;
    const int wave = t >> 6;
    const int lid = lane & 15;   // A: cat-in-tile / B: point / C: point col
    const int sub = lane >> 4;   // k-chunk (A,B) / cat row-quad (C)

    const float* eb = emb + (size_t)b * Nb * DIM;
    const int* lb = lab + (size_t)b * Nb;
    const float LN2 = 0.6931471805599453f;

    // ---- prototype fragments from sums/counts, built once by wave 0 ----
    if (wave == 0) {
        const float* gs = ws + WS_SUMS + b * NCAT * DIM;
        const float* gc = ws + WS_CNTS + b * NCAT;
        int np = 0;
        #pragma unroll
        for (int n = 0; n < 5; n++) {
            const int cat = n * 16 + lid;
            float q[8];
            float cnt = 0.f;
            if (cat < NCAT) {
                const float4* sp = (const float4*)(gs + cat * DIM + sub * 8);
                float4 s0 = sp[0], s1 = sp[1];
                cnt = gc[cat];
                const float ic = 1.0f / fmaxf(cnt, 1.0f);
                q[0] = s0.x * ic; q[1] = s0.y * ic; q[2] = s0.z * ic; q[3] = s0.w * ic;
                q[4] = s1.x * ic; q[5] = s1.y * ic; q[6] = s1.z * ic; q[7] = s1.w * ic;
            } else {
                #pragma unroll
                for (int j = 0; j < 8; j++) q[j] = 0.f;
            }
            float ss2 = 0.f;
            #pragma unroll
            for (int j = 0; j < 8; j++) ss2 += q[j] * q[j];
            ss2 += __shfl_xor(ss2, 16);
            ss2 += __shfl_xor(ss2, 32);
            const bool present = (cat < NCAT) && (cnt > 0.f) && !is_missing(cat);
            const float inv = present ? (1.0f / fmaxf(sqrtf(ss2), 1e-12f)) : 0.f;
            short8v hi8, lo8;
            #pragma unroll
            for (int j = 0; j < 8; j++) {
                float hf;
                hi8[j] = f2bf_hi(q[j] * inv, &hf);
                lo8[j] = f2bf(q[j] * inv - hf);
            }
            s_frag[n * 2][lane] = __builtin_bit_cast(u32x4, hi8);
            s_frag[n * 2 + 1][lane] = __builtin_bit_cast(u32x4, lo8);
            const unsigned long long bal = __ballot(present && sub == 0);
            np += (int)__popcll(bal & 0xFFFFull);
        }
        if (lane == 0) s_nabs = (float)(NCATP - np);
    }
    __syncthreads();
    const float nabs = s_nabs;

    float lacc = 0.f, dacc = 0.f, kacc = 0.f;

    #pragma unroll 1
    for (int p0 = (blk * 4 + wave) * 64; p0 < Nb; p0 += BPB * 4 * 64) {
        const int lv = lb[p0 + lane];          // one coalesced label load / iter
        const int l0 = __shfl(lv, lid);
        const int l1 = __shfl(lv, 16 + lid);
        const int l2 = __shfl(lv, 32 + lid);
        const int l3 = __shfl(lv, 48 + lid);
        point_group(p0 + lid,      l0, eb, s_frag, lane, nabs, sub, lacc, dacc, kacc);
        point_group(p0 + 16 + lid, l1, eb, s_frag, lane, nabs, sub, lacc, dacc, kacc);
        point_group(p0 + 32 + lid, l2, eb, s_frag, lane, nabs, sub, lacc, dacc, kacc);
        point_group(p0 + 48 + lid, l3, eb, s_frag, lane, nabs, sub, lacc, dacc, kacc);
    }

    // v = sum(log2 sums) - sum(label logits); k = kept count
    float v = lacc - dacc;
    #pragma unroll
    for (int m = 32; m >= 1; m >>= 1) {
        v += __shfl_xor(v, m);
        kacc += __shfl_xor(kacc, m);
    }
    if (lane == 0) {
        s_red[wave] = v;
        s_red[4 + wave] = kacc;
    }
    __syncthreads();
    if (t == 0) {
        float a = s_red[0] + s_red[1] + s_red[2] + s_red[3];
        float k = s_red[4] + s_red[5] + s_red[6] + s_red[7];
        unsafeAtomicAdd(lossout + b, LN2 * a);      // WS_LOSS (ln-space)
        unsafeAtomicAdd(lossout + BNUM + b, k);     // WS_KEEP
    }
}

__global__ void k_final(const float* __restrict__ ws, float* __restrict__ out) {
    if (threadIdx.x == 0 && blockIdx.x == 0) {
        float s = 0.f;
        for (int b = 0; b < BNUM; b++) {
            float l = ws[WS_LOSS + b];
            float k = ws[WS_KEEP + b];
            s += l / fmaxf(k, 1.0f);
        }
        out[0] = SEG_W * (s / BNUM);
    }
}

extern "C" void kernel_launch(void* const* d_in, const int* in_sizes, int n_in,
                              void* d_out, int out_size, void* d_ws, size_t ws_size,
                              hipStream_t stream) {
    const float* emb = (const float*)d_in[0];
    const int* lab = (const int*)d_in[1];
    float* ws = (float*)d_ws;
    float* out = (float*)d_out;
    const int total_pts = in_sizes[1];
    const int Nb = total_pts / BNUM;

    hipMemsetAsync(d_ws, 0, WS_TOTAL * sizeof(float), stream);
    constexpr int BPB_ACC = 192;   // 768 blocks -> 3 blocks/CU exact (LDS ~42.6KB/block)
    constexpr int BPB_LOSS = 256;  // 1024 blocks, 4 iters/wave of 4x16 points (R11 best)
    k_accum<BPB_ACC><<<dim3(BNUM * BPB_ACC), dim3(256), 0, stream>>>(emb, lab, ws, Nb);
    k_loss<BPB_LOSS><<<dim3(BNUM * BPB_LOSS), dim3(256), 0, stream>>>(
        emb, lab, ws, ws + WS_LOSS, Nb);
    k_final<<<1, 64, 0, stream>>>(ws, out);
}